// Round 11
// baseline (1368.883 us; speedup 1.0000x reference)
//
#include <hip/hip_runtime.h>
#include <cstdint>

#define BB 2048
#define SS 128
#define DD 512
#define HHID 2048
#define HRR 512
#define EE 8
#define CC 16
#define LSTEPS 5
#define MAXROWS 3072    // 2048 + 8*128, regions 128-aligned
#define NBLK128 24      // MAXROWS/128

typedef __bf16 bf16_t;
typedef __bf16 bf16x8 __attribute__((ext_vector_type(8)));
typedef float  f32x4  __attribute__((ext_vector_type(4)));

#define AS1 __attribute__((address_space(1)))
#define AS3 __attribute__((address_space(3)))

__device__ __forceinline__ void gload16(void* lds, const void* g){
  __builtin_amdgcn_global_load_lds((const AS1 uint32_t*)g, (AS3 uint32_t*)lds, 16, 0, 0);
}

__device__ __forceinline__ void split2(float v, bf16_t* h, bf16_t* l){
  bf16_t hh = (bf16_t)v;
  *h = hh;
  *l = (bf16_t)(v - (float)hh);
}

// ---------------- init ----------------
__global__ __launch_bounds__(256) void init_k(int* active, int* visits, int* cont,
                                              int* counts, double* total){
  int i = blockIdx.x*256 + threadIdx.x;
  if (i < BB){ active[i]=1; visits[i]=0; cont[i]=-1; }
  if (blockIdx.x == 0 && threadIdx.x < EE) counts[threadIdx.x]=0;
  if (i == 0) *total = 0.0;
}

// ---------------- fused setup: pool (blocks 0..2047) + 3x tsplit ----------------
__device__ __forceinline__ void tsplit_body(float* tile /*64x65*/, int t,
    const float* __restrict__ W, bf16_t* __restrict__ Th, bf16_t* __restrict__ Tl,
    int K, int N, int bx, int by, int bz)
{
  const size_t slice = (size_t)bz*(size_t)K*(size_t)N;
  const float* Ws = W + slice;
  bf16_t* Ths = Th + slice;
  bf16_t* Tls = Tl + slice;
  const int n0 = bx*64, k0 = by*64;
  const int tx = t & 63, ty = t >> 6;
  #pragma unroll
  for (int i=0;i<16;++i){
    int kk = (i<<2) + ty;
    tile[kk*65 + tx] = Ws[(size_t)(k0+kk)*N + n0 + tx];
  }
  __syncthreads();
  #pragma unroll
  for (int i=0;i<16;++i){
    int nn = (i<<2) + ty;
    float v = tile[tx*65 + nn];
    size_t o = (size_t)(n0+nn)*K + k0 + tx;
    bf16_t h = (bf16_t)v;
    Ths[o] = h;
    Tls[o] = (bf16_t)(v - (float)h);
  }
}

__global__ __launch_bounds__(256) void setup_k(
    const int* __restrict__ ids, const float* __restrict__ emb,
    float* __restrict__ rep, bf16_t* __restrict__ rhi, bf16_t* __restrict__ rlo,
    const float* __restrict__ rW1, bf16_t* __restrict__ rW1t_h, bf16_t* __restrict__ rW1t_l,
    const float* __restrict__ eW1, bf16_t* __restrict__ eW1t_h, bf16_t* __restrict__ eW1t_l,
    const float* __restrict__ eW2, bf16_t* __restrict__ eW2t_h, bf16_t* __restrict__ eW2t_l)
{
  __shared__ __align__(16) char smem[16640];   // max(pool 4608, tsplit 16640)
  const int bid = blockIdx.x, t = threadIdx.x;
  if (bid < BB){
    // ---- mean pool + rep split (unroll-8 in-flight loads) ----
    int* sid = (int*)smem;
    double* red = (double*)(smem + 512);       // [128][4]
    const int b = bid;
    if (t < SS) sid[t] = ids[b*SS + t];
    __syncthreads();
    const int half = t >> 7;
    const int c4   = t & 127;
    double a[4] = {0.0,0.0,0.0,0.0};
    for (int s = half; s < SS; s += 16){
      float4 v[8];
      #pragma unroll
      for (int u=0;u<8;++u)
        v[u] = *(const float4*)(emb + (size_t)sid[s + 2*u]*DD + (c4<<2));
      #pragma unroll
      for (int u=0;u<8;++u){
        a[0]+=(double)v[u].x; a[1]+=(double)v[u].y;
        a[2]+=(double)v[u].z; a[3]+=(double)v[u].w;
      }
    }
    if (half){
      #pragma unroll
      for (int j=0;j<4;++j) red[c4*4+j] = a[j];
    }
    __syncthreads();
    if (!half){
      float vv[4];
      #pragma unroll
      for (int j=0;j<4;++j) vv[j] = (float)((a[j] + red[c4*4+j]) * (1.0/SS));
      size_t o = (size_t)b*DD + (c4<<2);
      *(float4*)(rep + o) = make_float4(vv[0],vv[1],vv[2],vv[3]);
      #pragma unroll
      for (int j=0;j<4;++j) split2(vv[j], &rhi[o+j], &rlo[o+j]);
    }
  } else if (bid < BB + 64){
    int r = bid - BB;                          // rW1: (8 x 8)
    tsplit_body((float*)smem, t, rW1, rW1t_h, rW1t_l, DD, HRR, r & 7, r >> 3, 0);
  } else if (bid < BB + 64 + 2048){
    int r = bid - BB - 64;                     // eW1: (32 x 8 x 8)
    int z = r >> 8, rem = r & 255;
    tsplit_body((float*)smem, t, eW1, eW1t_h, eW1t_l, DD, HHID, rem & 31, rem >> 5, z);
  } else {
    int r = bid - BB - 64 - 2048;              // eW2: (8 x 32 x 8)
    int z = r >> 8, rem = r & 255;
    tsplit_body((float*)smem, t, eW2, eW2t_h, eW2t_l, HHID, DD, rem & 7, rem >> 3, z);
  }
}

// ---------------- expert-1 GEMM: 128x128 tile, per-wave 64x64, BK=32, dbuf ----------------
__global__ __launch_bounds__(256, 2) void e1gemm_k(
    const bf16_t* __restrict__ Agh, const bf16_t* __restrict__ Agl,
    const bf16_t* __restrict__ Wgh, const bf16_t* __restrict__ Wgl,
    const float* __restrict__ bias,
    bf16_t* __restrict__ Ohi, bf16_t* __restrict__ Olo,
    const bf16_t* __restrict__ zrow,
    const int* __restrict__ list, const int* __restrict__ blkexp)
{
  constexpr int K = DD;      // 512
  constexpr int N = HHID;    // 2048
  const int e = blkexp[blockIdx.y];
  if (e < 0) return;
  const int m0 = blockIdx.y * 128;
  const int n0 = blockIdx.x * 128;
  const bf16_t* Wh = Wgh + (size_t)e*(size_t)N*(size_t)K;
  const bf16_t* Wl = Wgl + (size_t)e*(size_t)N*(size_t)K;
  const float*  be = bias + (size_t)e*N;

  __shared__ __align__(16) bf16_t Ah[2][128*32], Al[2][128*32];
  __shared__ __align__(16) bf16_t Bh[2][128*32], Bl[2][128*32];
  __shared__ int sGi[128];

  const int t = threadIdx.x;
  const int L = t & 63, w = t >> 6;
  const int wm = w >> 1, wn = w & 1;

  if (t < 128) sGi[t] = list[m0 + t];
  __syncthreads();

  const int rIn = L >> 2;
  const int pSl = L & 3;

  auto stage = [&](int k0, int bb){
    if (w < 2){
      const bf16_t* gb = (w==0) ? Agh : Agl;
      bf16_t* sb = (w==0) ? Ah[bb] : Al[bb];
      #pragma unroll
      for (int i=0;i<8;++i){
        int r  = i*16 + rIn;
        int cs = pSl ^ ((r>>1)&3);
        int gi = sGi[r];
        const bf16_t* src = (gi >= 0) ? (gb + (size_t)gi*K + k0 + cs*8)
                                      : (zrow + cs*8);
        gload16((char*)sb + i*1024, src);
      }
    } else {
      const bf16_t* gb = (w==2) ? Wh : Wl;
      bf16_t* sb = (w==2) ? Bh[bb] : Bl[bb];
      #pragma unroll
      for (int i=0;i<8;++i){
        int r  = i*16 + rIn;
        int cs = pSl ^ ((r>>1)&3);
        gload16((char*)sb + i*1024, gb + (size_t)(n0+r)*K + k0 + cs*8);
      }
    }
  };

  f32x4 acc[4][4];
  #pragma unroll
  for (int i=0;i<4;++i)
    #pragma unroll
    for (int j=0;j<4;++j){ f32x4 z = {0.f,0.f,0.f,0.f}; acc[i][j]=z; }

  stage(0, 0);
  __syncthreads();

  const int g = L >> 4;
  constexpr int NT = K / 32;
  int cur = 0;
  for (int tk = 0; tk < NT; ++tk){
    if (tk + 1 < NT) stage((tk+1) << 5, cur ^ 1);

    bf16x8 avh[4], avl[4], bvh[4], bvl[4];
    #pragma unroll
    for (int mi=0;mi<4;++mi){
      int row = wm*64 + mi*16 + (L&15);
      int off = row*64 + ((g ^ ((row>>1)&3))<<4);
      avh[mi] = *(const bf16x8*)((const char*)Ah[cur] + off);
      avl[mi] = *(const bf16x8*)((const char*)Al[cur] + off);
    }
    #pragma unroll
    for (int ni=0;ni<4;++ni){
      int row = wn*64 + ni*16 + (L&15);
      int off = row*64 + ((g ^ ((row>>1)&3))<<4);
      bvh[ni] = *(const bf16x8*)((const char*)Bh[cur] + off);
      bvl[ni] = *(const bf16x8*)((const char*)Bl[cur] + off);
    }
    #pragma unroll
    for (int mi=0;mi<4;++mi)
      #pragma unroll
      for (int ni=0;ni<4;++ni){
        acc[mi][ni] = __builtin_amdgcn_mfma_f32_16x16x32_bf16(avh[mi], bvh[ni], acc[mi][ni], 0,0,0);
        acc[mi][ni] = __builtin_amdgcn_mfma_f32_16x16x32_bf16(avh[mi], bvl[ni], acc[mi][ni], 0,0,0);
        acc[mi][ni] = __builtin_amdgcn_mfma_f32_16x16x32_bf16(avl[mi], bvh[ni], acc[mi][ni], 0,0,0);
      }
    __syncthreads();
    cur ^= 1;
  }

  const int cL = L & 15, rL4 = (L>>4)<<2;
  #pragma unroll
  for (int mi=0;mi<4;++mi){
    #pragma unroll
    for (int ni=0;ni<4;++ni){
      const int col = n0 + wn*64 + ni*16 + cL;
      const float bv = be[col];
      #pragma unroll
      for (int r=0;r<4;++r){
        const int trow = wm*64 + mi*16 + rL4 + r;
        float val = fmaxf(acc[mi][ni][r] + bv, 0.f);
        size_t o = (size_t)(m0+trow)*(size_t)N + col;
        split2(val, &Ohi[o], &Olo[o]);
      }
    }
  }
}

// ---------------- router GEMM: 64x64, BK=64, dbuf (r8-proven structure) ----------------
__global__ __launch_bounds__(256, 2) void rgemm_k(
    const bf16_t* __restrict__ Agh, const bf16_t* __restrict__ Agl,
    const bf16_t* __restrict__ Wgh, const bf16_t* __restrict__ Wgl,
    const float* __restrict__ bias, float* __restrict__ Of)
{
  constexpr int K = DD, N = HRR, BM = 64, BN = 64;
  const int m0 = blockIdx.y*BM;
  const int n0 = blockIdx.x*BN;

  __shared__ __align__(16) bf16_t Ah[2][BM*64], Al[2][BM*64];
  __shared__ __align__(16) bf16_t Bh[2][BN*64], Bl[2][BN*64];

  const int t = threadIdx.x;
  const int L = t & 63, w = t >> 6;
  const int wm = w >> 1, wn = w & 1;

  const int rS = L>>3, sS = L&7;
  const int ss = sS ^ rS;

  auto stage = [&](int k0, int bb){
    if (w < 2){
      const bf16_t* gb = (w==0) ? Agh : Agl;
      bf16_t* sb = (w==0) ? Ah[bb] : Al[bb];
      #pragma unroll
      for (int i=0;i<8;++i){
        int r = i*8 + rS;
        gload16((char*)sb + i*1024, gb + (size_t)(m0+r)*K + k0 + ss*8);
      }
    } else {
      const bf16_t* gb = (w==2) ? Wgh : Wgl;
      bf16_t* sb = (w==2) ? Bh[bb] : Bl[bb];
      #pragma unroll
      for (int i=0;i<8;++i){
        int r = i*8 + rS;
        gload16((char*)sb + i*1024, gb + (size_t)(n0+r)*K + k0 + ss*8);
      }
    }
  };

  f32x4 acc[2][2];
  #pragma unroll
  for (int i=0;i<2;++i)
    #pragma unroll
    for (int j=0;j<2;++j){ f32x4 z = {0.f,0.f,0.f,0.f}; acc[i][j]=z; }

  stage(0, 0);
  __syncthreads();

  const int NT = K >> 6;
  int cur = 0;
  for (int tk = 0; tk < NT; ++tk){
    if (tk + 1 < NT) stage((tk+1) << 6, cur ^ 1);
    #pragma unroll
    for (int kk=0; kk<2; ++kk){
      const int g = (kk<<2) + (L>>4);
      bf16x8 avh[2], avl[2], bvh[2], bvl[2];
      #pragma unroll
      for (int mi=0;mi<2;++mi){
        int row = wm*32 + mi*16 + (L&15);
        int off = row*128 + ((g ^ (row&7))<<4);
        avh[mi] = *(const bf16x8*)((const char*)Ah[cur] + off);
        avl[mi] = *(const bf16x8*)((const char*)Al[cur] + off);
      }
      #pragma unroll
      for (int ni=0;ni<2;++ni){
        int row = wn*32 + ni*16 + (L&15);
        int off = row*128 + ((g ^ (row&7))<<4);
        bvh[ni] = *(const bf16x8*)((const char*)Bh[cur] + off);
        bvl[ni] = *(const bf16x8*)((const char*)Bl[cur] + off);
      }
      #pragma unroll
      for (int mi=0;mi<2;++mi)
        #pragma unroll
        for (int ni=0;ni<2;++ni){
          acc[mi][ni] = __builtin_amdgcn_mfma_f32_16x16x32_bf16(avh[mi], bvh[ni], acc[mi][ni], 0,0,0);
          acc[mi][ni] = __builtin_amdgcn_mfma_f32_16x16x32_bf16(avh[mi], bvl[ni], acc[mi][ni], 0,0,0);
          acc[mi][ni] = __builtin_amdgcn_mfma_f32_16x16x32_bf16(avl[mi], bvh[ni], acc[mi][ni], 0,0,0);
        }
    }
    __syncthreads();
    cur ^= 1;
  }

  const int cL = L & 15, rL4 = (L>>4)<<2;
  #pragma unroll
  for (int mi=0;mi<2;++mi){
    #pragma unroll
    for (int ni=0;ni<2;++ni){
      const int col = n0 + wn*32 + ni*16 + cL;
      const float bv = bias[col];
      #pragma unroll
      for (int r=0;r<4;++r){
        const int trow = wm*32 + mi*16 + rL4 + r;
        Of[(size_t)(m0+trow)*(size_t)N + col] = fmaxf(acc[mi][ni][r] + bv, 0.f);
      }
    }
  }
}

// ---------------- expert-2 GEMM, split-K=2: fp32 partials ----------------
__global__ __launch_bounds__(256, 2) void e2gemm_k(
    const bf16_t* __restrict__ Agh, const bf16_t* __restrict__ Agl,
    const bf16_t* __restrict__ Wgh, const bf16_t* __restrict__ Wgl,
    float* __restrict__ Cpart, const int* __restrict__ blkexp)
{
  constexpr int K = HHID, N = DD, BM = 64, BN = 64, KS = K/2;
  const int e = blkexp[(blockIdx.y*BM)>>7];
  if (e < 0) return;
  const int m0 = blockIdx.y*BM;
  const int n0 = blockIdx.x*BN;
  const int kbase = blockIdx.z * KS;
  const bf16_t* Wh = Wgh + (size_t)e*(size_t)N*(size_t)K;
  const bf16_t* Wl = Wgl + (size_t)e*(size_t)N*(size_t)K;
  float* Cp = Cpart + (size_t)blockIdx.z*MAXROWS*DD;

  __shared__ __align__(16) bf16_t Ah[2][BM*64], Al[2][BM*64];
  __shared__ __align__(16) bf16_t Bh[2][BN*64], Bl[2][BN*64];

  const int t = threadIdx.x;
  const int L = t & 63, w = t >> 6;
  const int wm = w >> 1, wn = w & 1;

  const int rS = L>>3, sS = L&7;
  const int ss = sS ^ rS;

  auto stage = [&](int k0, int bb){
    if (w < 2){
      const bf16_t* gb = (w==0) ? Agh : Agl;
      bf16_t* sb = (w==0) ? Ah[bb] : Al[bb];
      #pragma unroll
      for (int i=0;i<8;++i){
        int r = i*8 + rS;
        gload16((char*)sb + i*1024, gb + (size_t)(m0+r)*K + kbase + k0 + ss*8);
      }
    } else {
      const bf16_t* gb = (w==2) ? Wh : Wl;
      bf16_t* sb = (w==2) ? Bh[bb] : Bl[bb];
      #pragma unroll
      for (int i=0;i<8;++i){
        int r = i*8 + rS;
        gload16((char*)sb + i*1024, gb + (size_t)(n0+r)*K + kbase + k0 + ss*8);
      }
    }
  };

  f32x4 acc[2][2];
  #pragma unroll
  for (int i=0;i<2;++i)
    #pragma unroll
    for (int j=0;j<2;++j){ f32x4 z = {0.f,0.f,0.f,0.f}; acc[i][j]=z; }

  stage(0, 0);
  __syncthreads();

  const int NT = KS >> 6;
  int cur = 0;
  for (int tk = 0; tk < NT; ++tk){
    if (tk + 1 < NT) stage((tk+1) << 6, cur ^ 1);
    #pragma unroll
    for (int kk=0; kk<2; ++kk){
      const int g = (kk<<2) + (L>>4);
      bf16x8 avh[2], avl[2], bvh[2], bvl[2];
      #pragma unroll
      for (int mi=0;mi<2;++mi){
        int row = wm*32 + mi*16 + (L&15);
        int off = row*128 + ((g ^ (row&7))<<4);
        avh[mi] = *(const bf16x8*)((const char*)Ah[cur] + off);
        avl[mi] = *(const bf16x8*)((const char*)Al[cur] + off);
      }
      #pragma unroll
      for (int ni=0;ni<2;++ni){
        int row = wn*32 + ni*16 + (L&15);
        int off = row*128 + ((g ^ (row&7))<<4);
        bvh[ni] = *(const bf16x8*)((const char*)Bh[cur] + off);
        bvl[ni] = *(const bf16x8*)((const char*)Bl[cur] + off);
      }
      #pragma unroll
      for (int mi=0;mi<2;++mi)
        #pragma unroll
        for (int ni=0;ni<2;++ni){
          acc[mi][ni] = __builtin_amdgcn_mfma_f32_16x16x32_bf16(avh[mi], bvh[ni], acc[mi][ni], 0,0,0);
          acc[mi][ni] = __builtin_amdgcn_mfma_f32_16x16x32_bf16(avh[mi], bvl[ni], acc[mi][ni], 0,0,0);
          acc[mi][ni] = __builtin_amdgcn_mfma_f32_16x16x32_bf16(avl[mi], bvh[ni], acc[mi][ni], 0,0,0);
        }
    }
    __syncthreads();
    cur ^= 1;
  }

  const int cL = L & 15, rL4 = (L>>4)<<2;
  #pragma unroll
  for (int mi=0;mi<2;++mi){
    #pragma unroll
    for (int ni=0;ni<2;++ni){
      const int col = n0 + wn*32 + ni*16 + cL;
      #pragma unroll
      for (int r=0;r<4;++r){
        const int trow = wm*32 + mi*16 + rL4 + r;
        Cp[(size_t)(m0+trow)*(size_t)N + col] = acc[mi][ni][r];
      }
    }
  }
}

// ---------------- expert-2 combine: partials + bias + etag -> rep (+split) ----------------
__global__ __launch_bounds__(256) void e2fin_k(
    const float* __restrict__ Cpart, const float* __restrict__ eb2,
    const float* __restrict__ etag, const int* __restrict__ list,
    const int* __restrict__ blkexp,
    float* __restrict__ repf, bf16_t* __restrict__ rhi, bf16_t* __restrict__ rlo)
{
  const int m0 = blockIdx.x*64;
  const int e = blkexp[m0>>7];
  if (e < 0) return;
  const float* bb = eb2 + (size_t)e*DD;
  const float* xx = etag + (size_t)e*DD;
  const int r = threadIdx.x >> 2;          // 64 rows, 4 threads/row
  const int cq = threadIdx.x & 3;          // 128-col chunk
  const int orow = list[m0 + r];
  if (orow < 0) return;
  const float* c0 = Cpart + (size_t)(m0+r)*DD;
  const float* c1 = c0 + (size_t)MAXROWS*DD;
  float* rf = repf + (size_t)orow*DD;
  bf16_t* rh = rhi + (size_t)orow*DD;
  bf16_t* rl = rlo + (size_t)orow*DD;
  for (int c = cq*128; c < cq*128 + 128; c += 4){
    float4 v0 = *(const float4*)(c0 + c);
    float4 v1 = *(const float4*)(c1 + c);
    float4 bv = *(const float4*)(bb + c);
    float4 xv = *(const float4*)(xx + c);
    float vals[4] = { v0.x + v1.x + bv.x + xv.x,
                      v0.y + v1.y + bv.y + xv.y,
                      v0.z + v1.z + bv.z + xv.z,
                      v0.w + v1.w + bv.w + xv.w };
    *(float4*)(rf + c) = make_float4(vals[0], vals[1], vals[2], vals[3]);
    #pragma unroll
    for (int j=0;j<4;++j) split2(vals[j], &rh[c+j], &rl[c+j]);
  }
}

// ---------------- router decision: 4 rows/block, rW2 in LDS ----------------
__global__ __launch_bounds__(256) void decide_k(
    const float* __restrict__ hr, const float* __restrict__ rW2, const float* __restrict__ rb2,
    const float* __restrict__ rep, float* __restrict__ final_,
    float* __restrict__ ent, int* __restrict__ wasact,
    int* __restrict__ active, int* __restrict__ visits,
    int* __restrict__ cont, int* __restrict__ counts)
{
  __shared__ float srw2[HRR*9];
  const int t = threadIdx.x;
  for (int i = t; i < HRR*9; i += 256) srw2[i] = rW2[i];
  __syncthreads();

  const int w = t >> 6, lane = t & 63;
  const int b = blockIdx.x*4 + w;
  if (!active[b]){
    if (lane == 0){ ent[b]=0.f; wasact[b]=0; cont[b]=-1; }
    return;
  }
  const float* h = hr + (size_t)b*HRR;
  float p[9];
  #pragma unroll
  for (int j=0;j<9;++j) p[j]=0.f;
  for (int k=lane; k<HRR; k+=64){
    const float hv = h[k];
    const float* wr = srw2 + k*9;
    #pragma unroll
    for (int j=0;j<9;++j) p[j] = fmaf(hv, wr[j], p[j]);
  }
  #pragma unroll
  for (int off=32; off>=1; off>>=1){
    #pragma unroll
    for (int j=0;j<9;++j) p[j] += __shfl_xor(p[j], off, 64);
  }
  bool term = false;
  if (lane == 0){
    const int vis = visits[b];
    float lg[9];
    #pragma unroll
    for (int j=0;j<9;++j) lg[j] = p[j] + rb2[j];
    #pragma unroll
    for (int j=0;j<EE;++j) if ((vis>>j)&1) lg[j] = -1e9f;
    float m = lg[0];
    #pragma unroll
    for (int j=1;j<9;++j) m = fmaxf(m, lg[j]);
    float ex[9]; float s = 0.f;
    #pragma unroll
    for (int j=0;j<9;++j){ ex[j]=expf(lg[j]-m); s+=ex[j]; }
    float ev = 0.f;
    #pragma unroll
    for (int j=0;j<9;++j){ float pr=ex[j]/s; ev -= pr*logf(pr+1e-9f); }
    ent[b]=ev; wasact[b]=1;
    int arg=0; float best=lg[0];
    #pragma unroll
    for (int j=1;j<9;++j) if (lg[j]>best){ best=lg[j]; arg=j; }
    if (arg == EE){
      cont[b]=-1; active[b]=0; term=true;
    } else {
      cont[b]=arg; visits[b]=vis|(1<<arg);
      atomicAdd(&counts[arg],1);
    }
  }
  if (__shfl(term ? 1 : 0, 0, 64)){
    const float* rp = rep   + (size_t)b*DD;
    float*       fp = final_+ (size_t)b*DD;
    for (int d=lane; d<DD; d+=64) fp[d]=rp[d];
  }
}

// ---------------- fused: entropy reduce + offsets + pad fill + scatter ----------------
__global__ __launch_bounds__(256) void reduce_scatter_k(
    const float* __restrict__ ent, const int* __restrict__ wasact,
    const int* __restrict__ cont,
    int* __restrict__ counts, int* __restrict__ blkexp, int* __restrict__ list,
    double* __restrict__ total)
{
  const int t = threadIdx.x;
  double s = 0.0; int c = 0;
  for (int i=t;i<BB;i+=256){ s += (double)ent[i]; c += wasact[i]; }
  __shared__ double sd[256];
  __shared__ int    si[256];
  sd[t]=s; si[t]=c;
  __syncthreads();
  for (int off=128; off>=1; off>>=1){
    if (t < off){ sd[t]+=sd[t+off]; si[t]+=si[t+off]; }
    __syncthreads();
  }
  __shared__ int so[9]; __shared__ int sc[8]; __shared__ int scur[8];
  if (t == 0){
    if (si[0] > 0) *total += sd[0] / (double)si[0];
    int off = 0;
    for (int e2=0;e2<EE;++e2){
      so[e2]=off; sc[e2]=counts[e2]; scur[e2]=0;
      off += (counts[e2] + 127) & ~127;
    }
    so[8]=off;
    for (int r=0;r<NBLK128;++r){
      int ee=-1;
      for (int e2=0;e2<EE;++e2)
        if (r*128 >= so[e2] && (r+1)*128 <= so[e2+1]) ee=e2;
      blkexp[r]=ee;
    }
  }
  __syncthreads();
  for (int e2=0;e2<EE;++e2){
    for (int s2=so[e2]+sc[e2]+t; s2<so[e2+1]; s2+=256) list[s2]=-1;
  }
  for (int i=t;i<BB;i+=256){
    int e2 = cont[i];
    if (e2 >= 0){
      int p2 = atomicAdd(&scur[e2], 1);
      list[so[e2] + p2] = i;
    }
  }
  if (t < EE) counts[t]=0;
}

// ---------------- classifier + entropy output ----------------
__global__ __launch_bounds__(256) void cls_k(const float* __restrict__ rep,
    const float* __restrict__ final_, const int* __restrict__ active,
    const float* __restrict__ cW, const float* __restrict__ cb,
    const double* __restrict__ total, float* __restrict__ out)
{
  __shared__ float scw[DD*CC];
  const int t = threadIdx.x;
  for (int i = t; i < DD*CC; i += 256) scw[i] = cW[i];
  __syncthreads();

  const int w = t >> 6, lane = t & 63;
  const int b = blockIdx.x*4 + w;
  if (b == 0 && lane == 0) out[BB*CC] = (float)(*total);
  const float* src = active[b] ? rep + (size_t)b*DD : final_ + (size_t)b*DD;
  float c[CC];
  #pragma unroll
  for (int j=0;j<CC;++j) c[j]=0.f;
  for (int k=lane;k<DD;k+=64){
    float v = src[k];
    const float* wr = scw + k*CC;
    #pragma unroll
    for (int j=0;j<CC;++j) c[j] = fmaf(v, wr[j], c[j]);
  }
  #pragma unroll
  for (int off=32;off>=1;off>>=1){
    #pragma unroll
    for (int j=0;j<CC;++j) c[j] += __shfl_xor(c[j], off, 64);
  }
  if (lane == 0){
    float* op = out + (size_t)b*CC;
    #pragma unroll
    for (int j=0;j<CC;++j) op[j] = c[j] + cb[j];
  }
}

// ---------------- launch ----------------
extern "C" void kernel_launch(void* const* d_in, const int* in_sizes, int n_in,
                              void* d_out, int out_size, void* d_ws, size_t ws_size,
                              hipStream_t stream)
{
  const int*   ids = (const int*)  d_in[0];
  const float* emb = (const float*)d_in[1];
  const float* rW1 = (const float*)d_in[2];
  const float* rb1 = (const float*)d_in[3];
  const float* rW2 = (const float*)d_in[4];
  const float* rb2 = (const float*)d_in[5];
  const float* eW1 = (const float*)d_in[6];
  const float* eb1 = (const float*)d_in[7];
  const float* eW2 = (const float*)d_in[8];
  const float* eb2 = (const float*)d_in[9];
  const float* etag= (const float*)d_in[10];
  const float* cW  = (const float*)d_in[11];
  const float* cb  = (const float*)d_in[12];
  float* out = (float*)d_out;

  char* p = (char*)d_ws;
  auto alloc = [&](size_t bytes)->char*{
    char* r = p; p += (bytes + 255) & ~(size_t)255; return r;
  };
  float*  rep    = (float*) alloc((size_t)BB*DD*4);
  float*  hr     = (float*) alloc((size_t)BB*HRR*4);
  float*  final_ = (float*) alloc((size_t)BB*DD*4);
  bf16_t* rep_hi = (bf16_t*)alloc((size_t)BB*DD*2);
  bf16_t* rep_lo = (bf16_t*)alloc((size_t)BB*DD*2);
  bf16_t* hh_hi  = (bf16_t*)alloc((size_t)MAXROWS*HHID*2);
  bf16_t* hh_lo  = (bf16_t*)alloc((size_t)MAXROWS*HHID*2);
  float*  Cpart  = (float*) alloc((size_t)2*MAXROWS*DD*4);
  bf16_t* rW1t_h = (bf16_t*)alloc((size_t)DD*HRR*2);
  bf16_t* rW1t_l = (bf16_t*)alloc((size_t)DD*HRR*2);
  bf16_t* eW1t_h = (bf16_t*)alloc((size_t)EE*DD*HHID*2);
  bf16_t* eW1t_l = (bf16_t*)alloc((size_t)EE*DD*HHID*2);
  bf16_t* eW2t_h = (bf16_t*)alloc((size_t)EE*DD*HHID*2);
  bf16_t* eW2t_l = (bf16_t*)alloc((size_t)EE*DD*HHID*2);
  bf16_t* zrow   = (bf16_t*)alloc(4096);
  float*  ent    = (float*) alloc((size_t)BB*4);
  int* wasact = (int*)alloc((size_t)BB*4);
  int* cont   = (int*)alloc((size_t)BB*4);
  int* active = (int*)alloc((size_t)BB*4);
  int* visits = (int*)alloc((size_t)BB*4);
  int* list   = (int*)alloc((size_t)MAXROWS*4);
  int* counts = (int*)alloc(64);
  int* blkexp = (int*)alloc(NBLK128*4);
  double* total = (double*)alloc(16);

  hipMemsetAsync(final_, 0, (size_t)BB*DD*4, stream);
  hipMemsetAsync(zrow, 0, 4096, stream);
  init_k<<<BB/256, 256, 0, stream>>>(active, visits, cont, counts, total);

  // fused: pool (2048 blocks) + rW1 (64) + eW1 (2048) + eW2 (2048) transpose/split
  setup_k<<<BB + 64 + 2048 + 2048, 256, 0, stream>>>(
      ids, emb, rep, rep_hi, rep_lo,
      rW1, rW1t_h, rW1t_l, eW1, eW1t_h, eW1t_l, eW2, eW2t_h, eW2t_l);

  for (int step=0; step<LSTEPS; ++step){
    // router layer 1: hr = relu(rep @ rW1 + rb1)
    rgemm_k<<<dim3(HRR/64, BB/64), 256, 0, stream>>>(
        rep_hi, rep_lo, rW1t_h, rW1t_l, rb1, hr);

    decide_k<<<BB/4, 256, 0, stream>>>(hr, rW2, rb2, rep, final_, ent, wasact,
                                       active, visits, cont, counts);
    reduce_scatter_k<<<1, 256, 0, stream>>>(ent, wasact, cont, counts, blkexp, list, total);

    // expert layer 1: hh = relu(rep[list] @ eW1[e] + eb1[e]) -> split bf16
    e1gemm_k<<<dim3(HHID/128, NBLK128), 256, 0, stream>>>(
        rep_hi, rep_lo, eW1t_h, eW1t_l, eb1, hh_hi, hh_lo, zrow, list, blkexp);

    // expert layer 2 split-K=2: partials, then combine+scatter+split
    e2gemm_k<<<dim3(DD/64, MAXROWS/64, 2), 256, 0, stream>>>(
        hh_hi, hh_lo, eW2t_h, eW2t_l, Cpart, blkexp);
    e2fin_k<<<MAXROWS/64, 256, 0, stream>>>(
        Cpart, eb2, etag, list, blkexp, rep, rep_hi, rep_lo);
  }

  cls_k<<<BB/4, 256, 0, stream>>>(rep, final_, active, cW, cb, total, out);
}

// Round 12
// 597.223 us; speedup vs baseline: 2.2921x; 2.2921x over previous
//
#include <hip/hip_runtime.h>
#include <cstdint>

#define BB 2048
#define SS 128
#define DD 512
#define HHID 2048
#define HRR 512
#define EE 8
#define CC 16
#define LSTEPS 5
#define MAXROWS 3072    // 2048 + 8*128, regions 128-aligned
#define NBLK128 24      // MAXROWS/128

typedef __bf16 bf16_t;
typedef __bf16 bf16x8 __attribute__((ext_vector_type(8)));
typedef float  f32x4  __attribute__((ext_vector_type(4)));

#define AS1 __attribute__((address_space(1)))
#define AS3 __attribute__((address_space(3)))

__device__ __forceinline__ void gload16(void* lds, const void* g){
  __builtin_amdgcn_global_load_lds((const AS1 uint32_t*)g, (AS3 uint32_t*)lds, 16, 0, 0);
}

__device__ __forceinline__ void split2(float v, bf16_t* h, bf16_t* l){
  bf16_t hh = (bf16_t)v;
  *h = hh;
  *l = (bf16_t)(v - (float)hh);
}

// ---------------- init ----------------
__global__ __launch_bounds__(256) void init_k(int* active, int* visits, int* cont,
                                              int* counts, double* total){
  int i = blockIdx.x*256 + threadIdx.x;
  if (i < BB){ active[i]=1; visits[i]=0; cont[i]=-1; }
  if (blockIdx.x == 0 && threadIdx.x < EE) counts[threadIdx.x]=0;
  if (i == 0) *total = 0.0;
}

// ---------------- fused setup: pool (blocks 0..2047) + 3x tsplit ----------------
__device__ __forceinline__ void tsplit_body(float* tile /*64x65*/, int t,
    const float* __restrict__ W, bf16_t* __restrict__ Th, bf16_t* __restrict__ Tl,
    int K, int N, int bx, int by, int bz)
{
  const size_t slice = (size_t)bz*(size_t)K*(size_t)N;
  const float* Ws = W + slice;
  bf16_t* Ths = Th + slice;
  bf16_t* Tls = Tl + slice;
  const int n0 = bx*64, k0 = by*64;
  const int tx = t & 63, ty = t >> 6;
  #pragma unroll
  for (int i=0;i<16;++i){
    int kk = (i<<2) + ty;
    tile[kk*65 + tx] = Ws[(size_t)(k0+kk)*N + n0 + tx];
  }
  __syncthreads();
  #pragma unroll
  for (int i=0;i<16;++i){
    int nn = (i<<2) + ty;
    float v = tile[tx*65 + nn];
    size_t o = (size_t)(n0+nn)*K + k0 + tx;
    bf16_t h = (bf16_t)v;
    Ths[o] = h;
    Tls[o] = (bf16_t)(v - (float)h);
  }
}

__global__ __launch_bounds__(256) void setup_k(
    const int* __restrict__ ids, const float* __restrict__ emb,
    float* __restrict__ rep, bf16_t* __restrict__ rhi, bf16_t* __restrict__ rlo,
    const float* __restrict__ rW1, bf16_t* __restrict__ rW1t_h, bf16_t* __restrict__ rW1t_l,
    const float* __restrict__ eW1, bf16_t* __restrict__ eW1t_h, bf16_t* __restrict__ eW1t_l,
    const float* __restrict__ eW2, bf16_t* __restrict__ eW2t_h, bf16_t* __restrict__ eW2t_l)
{
  __shared__ __align__(16) char smem[16640];   // max(pool 4608, tsplit 16640)
  const int bid = blockIdx.x, t = threadIdx.x;
  if (bid < BB){
    // ---- mean pool + rep split (unroll-8 in-flight loads) ----
    int* sid = (int*)smem;
    double* red = (double*)(smem + 512);       // [128][4]
    const int b = bid;
    if (t < SS) sid[t] = ids[b*SS + t];
    __syncthreads();
    const int half = t >> 7;
    const int c4   = t & 127;
    double a[4] = {0.0,0.0,0.0,0.0};
    for (int s = half; s < SS; s += 16){
      float4 v[8];
      #pragma unroll
      for (int u=0;u<8;++u)
        v[u] = *(const float4*)(emb + (size_t)sid[s + 2*u]*DD + (c4<<2));
      #pragma unroll
      for (int u=0;u<8;++u){
        a[0]+=(double)v[u].x; a[1]+=(double)v[u].y;
        a[2]+=(double)v[u].z; a[3]+=(double)v[u].w;
      }
    }
    if (half){
      #pragma unroll
      for (int j=0;j<4;++j) red[c4*4+j] = a[j];
    }
    __syncthreads();
    if (!half){
      float vv[4];
      #pragma unroll
      for (int j=0;j<4;++j) vv[j] = (float)((a[j] + red[c4*4+j]) * (1.0/SS));
      size_t o = (size_t)b*DD + (c4<<2);
      *(float4*)(rep + o) = make_float4(vv[0],vv[1],vv[2],vv[3]);
      #pragma unroll
      for (int j=0;j<4;++j) split2(vv[j], &rhi[o+j], &rlo[o+j]);
    }
  } else if (bid < BB + 64){
    int r = bid - BB;                          // rW1: (8 x 8)
    tsplit_body((float*)smem, t, rW1, rW1t_h, rW1t_l, DD, HRR, r & 7, r >> 3, 0);
  } else if (bid < BB + 64 + 2048){
    int r = bid - BB - 64;                     // eW1: (32 x 8 x 8)
    int z = r >> 8, rem = r & 255;
    tsplit_body((float*)smem, t, eW1, eW1t_h, eW1t_l, DD, HHID, rem & 31, rem >> 5, z);
  } else {
    int r = bid - BB - 64 - 2048;              // eW2: (8 x 32 x 8)
    int z = r >> 8, rem = r & 255;
    tsplit_body((float*)smem, t, eW2, eW2t_h, eW2t_l, HHID, DD, rem & 7, rem >> 3, z);
  }
}

// ---------------- expert-1 GEMM: 128x128 tile, per-wave 64x64, BK=32, dbuf ----------------
__global__ __launch_bounds__(256, 2) void e1gemm_k(
    const bf16_t* __restrict__ Agh, const bf16_t* __restrict__ Agl,
    const bf16_t* __restrict__ Wgh, const bf16_t* __restrict__ Wgl,
    const float* __restrict__ bias,
    bf16_t* __restrict__ Ohi, bf16_t* __restrict__ Olo,
    const bf16_t* __restrict__ zrow,
    const int* __restrict__ list, const int* __restrict__ blkexp)
{
  constexpr int K = DD;      // 512
  constexpr int N = HHID;    // 2048
  const int e = blkexp[blockIdx.y];
  if (e < 0) return;
  const int m0 = blockIdx.y * 128;
  const int n0 = blockIdx.x * 128;
  const bf16_t* Wh = Wgh + (size_t)e*(size_t)N*(size_t)K;
  const bf16_t* Wl = Wgl + (size_t)e*(size_t)N*(size_t)K;
  const float*  be = bias + (size_t)e*N;

  __shared__ __align__(16) bf16_t Ah[2][128*32], Al[2][128*32];
  __shared__ __align__(16) bf16_t Bh[2][128*32], Bl[2][128*32];
  __shared__ int sGi[128];

  const int t = threadIdx.x;
  const int L = t & 63, w = t >> 6;
  const int wm = w >> 1, wn = w & 1;

  if (t < 128) sGi[t] = list[m0 + t];
  __syncthreads();

  const int rIn = L >> 2;
  const int pSl = L & 3;

  auto stage = [&](int k0, int bb){
    if (w < 2){
      const bf16_t* gb = (w==0) ? Agh : Agl;
      bf16_t* sb = (w==0) ? Ah[bb] : Al[bb];
      #pragma unroll
      for (int i=0;i<8;++i){
        int r  = i*16 + rIn;
        int cs = pSl ^ ((r>>1)&3);
        int gi = sGi[r];
        const bf16_t* src = (gi >= 0) ? (gb + (size_t)gi*K + k0 + cs*8)
                                      : (zrow + cs*8);
        gload16((char*)sb + i*1024, src);
      }
    } else {
      const bf16_t* gb = (w==2) ? Wh : Wl;
      bf16_t* sb = (w==2) ? Bh[bb] : Bl[bb];
      #pragma unroll
      for (int i=0;i<8;++i){
        int r  = i*16 + rIn;
        int cs = pSl ^ ((r>>1)&3);
        gload16((char*)sb + i*1024, gb + (size_t)(n0+r)*K + k0 + cs*8);
      }
    }
  };

  f32x4 acc[4][4];
  #pragma unroll
  for (int i=0;i<4;++i)
    #pragma unroll
    for (int j=0;j<4;++j){ f32x4 z = {0.f,0.f,0.f,0.f}; acc[i][j]=z; }

  stage(0, 0);
  __syncthreads();

  const int g = L >> 4;
  constexpr int NT = K / 32;
  int cur = 0;
  for (int tk = 0; tk < NT; ++tk){
    if (tk + 1 < NT) stage((tk+1) << 5, cur ^ 1);

    bf16x8 avh[4], avl[4], bvh[4], bvl[4];
    #pragma unroll
    for (int mi=0;mi<4;++mi){
      int row = wm*64 + mi*16 + (L&15);
      int off = row*64 + ((g ^ ((row>>1)&3))<<4);
      avh[mi] = *(const bf16x8*)((const char*)Ah[cur] + off);
      avl[mi] = *(const bf16x8*)((const char*)Al[cur] + off);
    }
    #pragma unroll
    for (int ni=0;ni<4;++ni){
      int row = wn*64 + ni*16 + (L&15);
      int off = row*64 + ((g ^ ((row>>1)&3))<<4);
      bvh[ni] = *(const bf16x8*)((const char*)Bh[cur] + off);
      bvl[ni] = *(const bf16x8*)((const char*)Bl[cur] + off);
    }
    #pragma unroll
    for (int mi=0;mi<4;++mi)
      #pragma unroll
      for (int ni=0;ni<4;++ni){
        acc[mi][ni] = __builtin_amdgcn_mfma_f32_16x16x32_bf16(avh[mi], bvh[ni], acc[mi][ni], 0,0,0);
        acc[mi][ni] = __builtin_amdgcn_mfma_f32_16x16x32_bf16(avh[mi], bvl[ni], acc[mi][ni], 0,0,0);
        acc[mi][ni] = __builtin_amdgcn_mfma_f32_16x16x32_bf16(avl[mi], bvh[ni], acc[mi][ni], 0,0,0);
      }
    __syncthreads();
    cur ^= 1;
  }

  const int cL = L & 15, rL4 = (L>>4)<<2;
  #pragma unroll
  for (int mi=0;mi<4;++mi){
    #pragma unroll
    for (int ni=0;ni<4;++ni){
      const int col = n0 + wn*64 + ni*16 + cL;
      const float bv = be[col];
      #pragma unroll
      for (int r=0;r<4;++r){
        const int trow = wm*64 + mi*16 + rL4 + r;
        float val = fmaxf(acc[mi][ni][r] + bv, 0.f);
        size_t o = (size_t)(m0+trow)*(size_t)N + col;
        split2(val, &Ohi[o], &Olo[o]);
      }
    }
  }
}

// ---------------- bf16x3 MFMA GEMM, double-buffered pipeline (2x2 waves) ----------------
template<int BM, int BN, bool RELU, bool EXPERT, bool GATHER, bool SCATTER, bool EXTRA, bool SPLITOUT>
__global__ __launch_bounds__(256, 2) void mgemm_k(
    const bf16_t* __restrict__ Agh, const bf16_t* __restrict__ Agl,
    const bf16_t* __restrict__ Wgh, const bf16_t* __restrict__ Wgl,
    const float* __restrict__ bias, const float* __restrict__ extra,
    float* __restrict__ Of, bf16_t* __restrict__ Ohi, bf16_t* __restrict__ Olo,
    float* __restrict__ repf, bf16_t* __restrict__ rhi, bf16_t* __restrict__ rlo,
    const bf16_t* __restrict__ zrow,
    const int* __restrict__ list, const int* __restrict__ blkexp,
    int K, int N)
{
  int e = 0;
  if constexpr (EXPERT){ e = blkexp[(blockIdx.y*BM)>>7]; if (e < 0) return; }
  const int m0 = blockIdx.y*BM;
  const int n0 = blockIdx.x*BN;
  const bf16_t* Wh = Wgh + (EXPERT ? (size_t)e*(size_t)N*(size_t)K : 0);
  const bf16_t* Wl = Wgl + (EXPERT ? (size_t)e*(size_t)N*(size_t)K : 0);
  const float*  be = bias + (EXPERT ? (size_t)e*N : 0);
  const float*  xe = EXTRA ? (extra + (size_t)e*(size_t)N) : nullptr;

  __shared__ __align__(16) bf16_t Ah[2][BM*64], Al[2][BM*64];
  __shared__ __align__(16) bf16_t Bh[2][BN*64], Bl[2][BN*64];
  __shared__ int sGi[BM];

  const int t = threadIdx.x;
  const int L = t & 63, w = t >> 6;

  constexpr int MI = BM/32;
  constexpr int NI = BN/32;
  const int wm = w >> 1;
  const int wn = w & 1;

  constexpr int AQ = BM/8;
  constexpr int BQ = BN/8;
  const int rS = L>>3, sS = L&7;
  const int ss = sS ^ rS;

  if constexpr (GATHER || SCATTER){
    if (t < BM) sGi[t] = list[m0 + t];
  }
  if constexpr (GATHER) __syncthreads();

  auto stage = [&](int k0, int bb){
    if (w < 2){
      const bf16_t* gb = (w==0) ? Agh : Agl;
      bf16_t* sb = (w==0) ? Ah[bb] : Al[bb];
      #pragma unroll
      for (int i=0;i<AQ;++i){
        int r = i*8 + rS;
        const bf16_t* src;
        if constexpr (GATHER){
          int gi = sGi[r];
          src = (gi >= 0) ? (gb + (size_t)gi*K + k0 + ss*8) : (zrow + ss*8);
        } else {
          src = gb + (size_t)(m0+r)*K + k0 + ss*8;
        }
        gload16((char*)sb + i*1024, src);
      }
    } else {
      const bf16_t* gb = (w==2) ? Wh : Wl;
      bf16_t* sb = (w==2) ? Bh[bb] : Bl[bb];
      #pragma unroll
      for (int i=0;i<BQ;++i){
        int r = i*8 + rS;
        gload16((char*)sb + i*1024, gb + (size_t)(n0+r)*K + k0 + ss*8);
      }
    }
  };

  f32x4 acc[MI][NI];
  #pragma unroll
  for (int i=0;i<MI;++i)
    #pragma unroll
    for (int j=0;j<NI;++j){ f32x4 z = {0.f,0.f,0.f,0.f}; acc[i][j]=z; }

  stage(0, 0);
  __syncthreads();

  const int NT = K >> 6;
  int cur = 0;
  for (int tk = 0; tk < NT; ++tk){
    if (tk + 1 < NT) stage((tk+1) << 6, cur ^ 1);

    #pragma unroll
    for (int kk=0; kk<2; ++kk){
      const int g = (kk<<2) + (L>>4);
      bf16x8 avh[MI], avl[MI];
      #pragma unroll
      for (int mi=0;mi<MI;++mi){
        int row = wm*(BM/2) + mi*16 + (L&15);
        int off = row*128 + ((g ^ (row&7))<<4);
        avh[mi] = *(const bf16x8*)((const char*)Ah[cur] + off);
        avl[mi] = *(const bf16x8*)((const char*)Al[cur] + off);
      }
      bf16x8 bvh[NI], bvl[NI];
      #pragma unroll
      for (int ni=0;ni<NI;++ni){
        int row = wn*(BN/2) + ni*16 + (L&15);
        int off = row*128 + ((g ^ (row&7))<<4);
        bvh[ni] = *(const bf16x8*)((const char*)Bh[cur] + off);
        bvl[ni] = *(const bf16x8*)((const char*)Bl[cur] + off);
      }
      #pragma unroll
      for (int mi=0;mi<MI;++mi)
        #pragma unroll
        for (int ni=0;ni<NI;++ni){
          acc[mi][ni] = __builtin_amdgcn_mfma_f32_16x16x32_bf16(avh[mi], bvh[ni], acc[mi][ni], 0,0,0);
          acc[mi][ni] = __builtin_amdgcn_mfma_f32_16x16x32_bf16(avh[mi], bvl[ni], acc[mi][ni], 0,0,0);
          acc[mi][ni] = __builtin_amdgcn_mfma_f32_16x16x32_bf16(avl[mi], bvh[ni], acc[mi][ni], 0,0,0);
        }
    }
    __syncthreads();
    cur ^= 1;
  }

  const int cL = L & 15, rL4 = (L>>4)<<2;
  #pragma unroll
  for (int mi=0;mi<MI;++mi){
    #pragma unroll
    for (int ni=0;ni<NI;++ni){
      const int col = n0 + wn*(BN/2) + ni*16 + cL;
      float bv = be[col];
      if constexpr (EXTRA) bv += xe[col];
      #pragma unroll
      for (int r=0;r<4;++r){
        const int trow = wm*(BM/2) + mi*16 + rL4 + r;
        float val = acc[mi][ni][r] + bv;
        if constexpr (RELU) val = fmaxf(val, 0.f);
        if constexpr (SCATTER){
          int orow = sGi[trow];
          if (orow >= 0){
            size_t o = (size_t)orow*DD + col;
            repf[o] = val;
            split2(val, &rhi[o], &rlo[o]);
          }
        } else if constexpr (SPLITOUT){
          size_t o = (size_t)(m0+trow)*(size_t)N + col;
          split2(val, &Ohi[o], &Olo[o]);
        } else {
          Of[(size_t)(m0+trow)*(size_t)N + col] = val;
        }
      }
    }
  }
}

// ---------------- router decision: 4 rows/block, rW2 in LDS ----------------
__global__ __launch_bounds__(256) void decide_k(
    const float* __restrict__ hr, const float* __restrict__ rW2, const float* __restrict__ rb2,
    const float* __restrict__ rep, float* __restrict__ final_,
    float* __restrict__ ent, int* __restrict__ wasact,
    int* __restrict__ active, int* __restrict__ visits,
    int* __restrict__ cont, int* __restrict__ counts)
{
  __shared__ float srw2[HRR*9];
  const int t = threadIdx.x;
  for (int i = t; i < HRR*9; i += 256) srw2[i] = rW2[i];
  __syncthreads();

  const int w = t >> 6, lane = t & 63;
  const int b = blockIdx.x*4 + w;
  if (!active[b]){
    if (lane == 0){ ent[b]=0.f; wasact[b]=0; cont[b]=-1; }
    return;
  }
  const float* h = hr + (size_t)b*HRR;
  float p[9];
  #pragma unroll
  for (int j=0;j<9;++j) p[j]=0.f;
  for (int k=lane; k<HRR; k+=64){
    const float hv = h[k];
    const float* wr = srw2 + k*9;
    #pragma unroll
    for (int j=0;j<9;++j) p[j] = fmaf(hv, wr[j], p[j]);
  }
  #pragma unroll
  for (int off=32; off>=1; off>>=1){
    #pragma unroll
    for (int j=0;j<9;++j) p[j] += __shfl_xor(p[j], off, 64);
  }
  bool term = false;
  if (lane == 0){
    const int vis = visits[b];
    float lg[9];
    #pragma unroll
    for (int j=0;j<9;++j) lg[j] = p[j] + rb2[j];
    #pragma unroll
    for (int j=0;j<EE;++j) if ((vis>>j)&1) lg[j] = -1e9f;
    float m = lg[0];
    #pragma unroll
    for (int j=1;j<9;++j) m = fmaxf(m, lg[j]);
    float ex[9]; float s = 0.f;
    #pragma unroll
    for (int j=0;j<9;++j){ ex[j]=expf(lg[j]-m); s+=ex[j]; }
    float ev = 0.f;
    #pragma unroll
    for (int j=0;j<9;++j){ float pr=ex[j]/s; ev -= pr*logf(pr+1e-9f); }
    ent[b]=ev; wasact[b]=1;
    int arg=0; float best=lg[0];
    #pragma unroll
    for (int j=1;j<9;++j) if (lg[j]>best){ best=lg[j]; arg=j; }
    if (arg == EE){
      cont[b]=-1; active[b]=0; term=true;
    } else {
      cont[b]=arg; visits[b]=vis|(1<<arg);
      atomicAdd(&counts[arg],1);
    }
  }
  if (__shfl(term ? 1 : 0, 0, 64)){
    const float* rp = rep   + (size_t)b*DD;
    float*       fp = final_+ (size_t)b*DD;
    for (int d=lane; d<DD; d+=64) fp[d]=rp[d];
  }
}

// ---------------- fused: entropy reduce + offsets + pad fill + scatter ----------------
__global__ __launch_bounds__(256) void reduce_scatter_k(
    const float* __restrict__ ent, const int* __restrict__ wasact,
    const int* __restrict__ cont,
    int* __restrict__ counts, int* __restrict__ blkexp, int* __restrict__ list,
    double* __restrict__ total)
{
  const int t = threadIdx.x;
  double s = 0.0; int c = 0;
  for (int i=t;i<BB;i+=256){ s += (double)ent[i]; c += wasact[i]; }
  __shared__ double sd[256];
  __shared__ int    si[256];
  sd[t]=s; si[t]=c;
  __syncthreads();
  for (int off=128; off>=1; off>>=1){
    if (t < off){ sd[t]+=sd[t+off]; si[t]+=si[t+off]; }
    __syncthreads();
  }
  __shared__ int so[9]; __shared__ int sc[8]; __shared__ int scur[8];
  if (t == 0){
    if (si[0] > 0) *total += sd[0] / (double)si[0];
    int off = 0;
    for (int e2=0;e2<EE;++e2){
      so[e2]=off; sc[e2]=counts[e2]; scur[e2]=0;
      off += (counts[e2] + 127) & ~127;
    }
    so[8]=off;
    for (int r=0;r<NBLK128;++r){
      int ee=-1;
      for (int e2=0;e2<EE;++e2)
        if (r*128 >= so[e2] && (r+1)*128 <= so[e2+1]) ee=e2;
      blkexp[r]=ee;
    }
  }
  __syncthreads();
  for (int e2=0;e2<EE;++e2){
    for (int s2=so[e2]+sc[e2]+t; s2<so[e2+1]; s2+=256) list[s2]=-1;
  }
  for (int i=t;i<BB;i+=256){
    int e2 = cont[i];
    if (e2 >= 0){
      int p2 = atomicAdd(&scur[e2], 1);
      list[so[e2] + p2] = i;
    }
  }
  if (t < EE) counts[t]=0;
}

// ---------------- classifier + entropy output: 4 rows/block, cW in LDS ----------------
__global__ __launch_bounds__(256) void cls_k(const float* __restrict__ rep,
    const float* __restrict__ final_, const int* __restrict__ active,
    const float* __restrict__ cW, const float* __restrict__ cb,
    const double* __restrict__ total, float* __restrict__ out)
{
  __shared__ float scw[DD*CC];
  const int t = threadIdx.x;
  for (int i = t; i < DD*CC; i += 256) scw[i] = cW[i];
  __syncthreads();

  const int w = t >> 6, lane = t & 63;
  const int b = blockIdx.x*4 + w;
  if (b == 0 && lane == 0) out[BB*CC] = (float)(*total);
  const float* src = active[b] ? rep + (size_t)b*DD : final_ + (size_t)b*DD;
  float c[CC];
  #pragma unroll
  for (int j=0;j<CC;++j) c[j]=0.f;
  for (int k=lane;k<DD;k+=64){
    float v = src[k];
    const float* wr = scw + k*CC;
    #pragma unroll
    for (int j=0;j<CC;++j) c[j] = fmaf(v, wr[j], c[j]);
  }
  #pragma unroll
  for (int off=32;off>=1;off>>=1){
    #pragma unroll
    for (int j=0;j<CC;++j) c[j] += __shfl_xor(c[j], off, 64);
  }
  if (lane == 0){
    float* op = out + (size_t)b*CC;
    #pragma unroll
    for (int j=0;j<CC;++j) op[j] = c[j] + cb[j];
  }
}

// ---------------- launch ----------------
extern "C" void kernel_launch(void* const* d_in, const int* in_sizes, int n_in,
                              void* d_out, int out_size, void* d_ws, size_t ws_size,
                              hipStream_t stream)
{
  const int*   ids = (const int*)  d_in[0];
  const float* emb = (const float*)d_in[1];
  const float* rW1 = (const float*)d_in[2];
  const float* rb1 = (const float*)d_in[3];
  const float* rW2 = (const float*)d_in[4];
  const float* rb2 = (const float*)d_in[5];
  const float* eW1 = (const float*)d_in[6];
  const float* eb1 = (const float*)d_in[7];
  const float* eW2 = (const float*)d_in[8];
  const float* eb2 = (const float*)d_in[9];
  const float* etag= (const float*)d_in[10];
  const float* cW  = (const float*)d_in[11];
  const float* cb  = (const float*)d_in[12];
  float* out = (float*)d_out;

  char* p = (char*)d_ws;
  auto alloc = [&](size_t bytes)->char*{
    char* r = p; p += (bytes + 255) & ~(size_t)255; return r;
  };
  float*  rep    = (float*) alloc((size_t)BB*DD*4);
  float*  hr     = (float*) alloc((size_t)BB*HRR*4);
  float*  final_ = (float*) alloc((size_t)BB*DD*4);
  bf16_t* rep_hi = (bf16_t*)alloc((size_t)BB*DD*2);
  bf16_t* rep_lo = (bf16_t*)alloc((size_t)BB*DD*2);
  bf16_t* hh_hi  = (bf16_t*)alloc((size_t)MAXROWS*HHID*2);
  bf16_t* hh_lo  = (bf16_t*)alloc((size_t)MAXROWS*HHID*2);
  bf16_t* rW1t_h = (bf16_t*)alloc((size_t)DD*HRR*2);
  bf16_t* rW1t_l = (bf16_t*)alloc((size_t)DD*HRR*2);
  bf16_t* eW1t_h = (bf16_t*)alloc((size_t)EE*DD*HHID*2);
  bf16_t* eW1t_l = (bf16_t*)alloc((size_t)EE*DD*HHID*2);
  bf16_t* eW2t_h = (bf16_t*)alloc((size_t)EE*DD*HHID*2);
  bf16_t* eW2t_l = (bf16_t*)alloc((size_t)EE*DD*HHID*2);
  bf16_t* zrow   = (bf16_t*)alloc(4096);
  float*  ent    = (float*) alloc((size_t)BB*4);
  int* wasact = (int*)alloc((size_t)BB*4);
  int* cont   = (int*)alloc((size_t)BB*4);
  int* active = (int*)alloc((size_t)BB*4);
  int* visits = (int*)alloc((size_t)BB*4);
  int* list   = (int*)alloc((size_t)MAXROWS*4);
  int* counts = (int*)alloc(64);
  int* blkexp = (int*)alloc(NBLK128*4);
  double* total = (double*)alloc(16);

  hipMemsetAsync(final_, 0, (size_t)BB*DD*4, stream);
  hipMemsetAsync(zrow, 0, 4096, stream);
  init_k<<<BB/256, 256, 0, stream>>>(active, visits, cont, counts, total);

  // fused: pool (2048 blocks) + rW1 (64) + eW1 (2048) + eW2 (2048) transpose/split
  setup_k<<<BB + 64 + 2048 + 2048, 256, 0, stream>>>(
      ids, emb, rep, rep_hi, rep_lo,
      rW1, rW1t_h, rW1t_l, eW1, eW1t_h, eW1t_l, eW2, eW2t_h, eW2t_l);

  for (int step=0; step<LSTEPS; ++step){
    // router layer 1: hr = relu(rep @ rW1 + rb1)
    mgemm_k<64,64, true,false,false,false,false,false><<<dim3(HRR/64, BB/64), 256, 0, stream>>>(
        rep_hi, rep_lo, rW1t_h, rW1t_l, rb1, nullptr,
        hr, nullptr, nullptr, nullptr, nullptr, nullptr,
        zrow, nullptr, nullptr, DD, HRR);

    decide_k<<<BB/4, 256, 0, stream>>>(hr, rW2, rb2, rep, final_, ent, wasact,
                                       active, visits, cont, counts);
    reduce_scatter_k<<<1, 256, 0, stream>>>(ent, wasact, cont, counts, blkexp, list, total);

    // expert layer 1: hh = relu(rep[list] @ eW1[e] + eb1[e]) -> split bf16
    e1gemm_k<<<dim3(HHID/128, NBLK128), 256, 0, stream>>>(
        rep_hi, rep_lo, eW1t_h, eW1t_l, eb1, hh_hi, hh_lo, zrow, list, blkexp);

    // expert layer 2: rep[list] = hh @ eW2[e] + eb2[e] + etag[e]  (scatter + re-split)
    mgemm_k<64,64, false,true,false,true,true,false><<<dim3(DD/64, MAXROWS/64), 256, 0, stream>>>(
        hh_hi, hh_lo, eW2t_h, eW2t_l, eb2, etag,
        nullptr, nullptr, nullptr, rep, rep_hi, rep_lo,
        zrow, list, blkexp, HHID, DD);
  }

  cls_k<<<BB/4, 256, 0, stream>>>(rep, final_, active, cW, cb, total, out);
}